// Round 9
// baseline (93.229 us; speedup 1.0000x reference)
//
#include <hip/hip_runtime.h>
#include <hip/hip_fp16.h>

#define N 8192
#define D 128
#define MARGIN 0.3f

typedef __fp16 half_t;
typedef __attribute__((ext_vector_type(8))) __fp16 half8;
typedef __attribute__((ext_vector_type(4))) float f32x4;

#define AS1C(p) ((const __attribute__((address_space(1))) void*)(p))
#define AS3(p)  ((__attribute__((address_space(3))) void*)(p))

// ---------------- prep: norms + packed fp16 tiles + packed {label,norm} ------
// xp packed MFMA-native: within tile t (16 rows), flat slot i = ks4*16 + r16
// holds row t*16+r16, k = (i>>4)*8 .. +8.  (identical to R7/R8 layout)
__global__ void triplet_prep(const float* __restrict__ x,
                             const int* __restrict__ labels,
                             half_t* __restrict__ xp,
                             float2* __restrict__ lnj,
                             float* __restrict__ gacc) {
    __shared__ float wpart[4][16];
    const int b   = blockIdx.x;
    const int i   = threadIdx.x;
    if (b == 0 && i < 3) gacc[i] = 0.f;      // [0]=sum [1]=count [2]=ticket
    const int row = b * 16 + (i & 15);
    const int kb  = i >> 4;
    const float* rp = x + (size_t)row * D + kb * 8;
    float v[8];
#pragma unroll
    for (int e = 0; e < 8; ++e) v[e] = rp[e];
    half_t h[8];
#pragma unroll
    for (int e = 0; e < 8; ++e) h[e] = (half_t)v[e];
    *(half8*)(xp + ((size_t)b * 256 + i) * 8) = *(const half8*)h;

    float s = 0.f;
#pragma unroll
    for (int e = 0; e < 8; ++e) s = fmaf(v[e], v[e], s);
    s += __shfl_xor(s, 16);
    s += __shfl_xor(s, 32);                  // sum over the wave's 4 kb-lanes per row
    const int w = i >> 6, lane = i & 63;
    if (lane < 16) wpart[w][lane] = s;
    __syncthreads();
    if (i < 16) {
        const int r = b * 16 + i;
        float nv = wpart[0][i] + wpart[1][i] + wpart[2][i] + wpart[3][i];
        float2 p; p.x = __int_as_float(labels[r]); p.y = nv;
        lnj[r] = p;
    }
}

// ---------------- main: A-in-regs, block-cooperative LDS-staged B ------------
// 512 blocks x 512 threads (8 waves). Block = 512 rows x 256-col chunk; all 8
// waves share the B stream -> staged ONCE per block into LDS (4KB/substep,
// double-buffered, global_load_lds, 2-phase: stage t+1 issued before compute t,
// one vmcnt(0)+barrier per substep). A frags register-resident, pre-scaled by
// -2; acc seeded with n_j so acc = n_j - 2g. {label,norm} staged to LDS once.

#define POISON(ACC) {                                                   \
    _Pragma("unroll")                                                   \
    for (int rg = 0; rg < 4; ++rg)                                      \
        ACC[rg] = (diagl && rg == drg) ? -1e30f : ACC[rg];              \
}

#define EPI(ACC, FI, LJC) {                                             \
    _Pragma("unroll")                                                   \
    for (int rg = 0; rg < 4; ++rg) {                                    \
        float c = ACC[rg];                                              \
        bool same = (li[(FI) * 4 + rg] == (LJC));                       \
        mpos[(FI)*4+rg] = same ? fmaxf(mpos[(FI)*4+rg], c) : mpos[(FI)*4+rg]; \
        mneg[(FI)*4+rg] = same ? mneg[(FI)*4+rg] : fminf(mneg[(FI)*4+rg], c); \
    }                                                                   \
}

__launch_bounds__(512)
__global__ void triplet_main(const half_t* __restrict__ xp,
                             const float2* __restrict__ lnjg,
                             const int* __restrict__ labels,
                             float* __restrict__ ppos,
                             float* __restrict__ pneg) {
    __shared__ __align__(16) half_t Bs[2][2048];   // 2 x 4 KiB
    __shared__ __align__(16) float2 Lns[256];      // 2 KiB

    const int tid   = threadIdx.x;
    const int lane  = tid & 63;
    const int b     = blockIdx.x;                   // 0..511
    const int chunk = b & 31;                       // shared by all 8 waves
    const int rowg  = (b >> 5) * 8 + (tid >> 6);    // 0..127
    const int lrow  = lane >> 4;
    const int lcol  = lane & 15;
    const int rowbase = rowg * 64;
    const int colbase = chunk * 256;
    const bool diagl = (lrow == (lcol >> 2));
    const int  drg   = lcol & 3;

    // ---- prologue staging: B(tile0) 4KB by waves 0-3, lnj 2KB by wave 4 ----
    if (tid < 256)
        __builtin_amdgcn_global_load_lds(
            AS1C(xp + (size_t)(colbase >> 4) * 2048 + tid * 8),
            AS3(&Bs[0][tid * 8]), 16, 0, 0);
    else if (tid < 384) {
        const int i = tid - 256;
        __builtin_amdgcn_global_load_lds(
            AS1C((const char*)(lnjg + colbase) + i * 16),
            AS3((char*)&Lns[0] + i * 16), 16, 0, 0);
    }

    // ---- A fragments from packed tiles; pre-scaled by -2 ----
    half8 af[4][4];
#pragma unroll
    for (int fi = 0; fi < 4; ++fi) {
        const half_t* ap = xp + ((size_t)(rowbase >> 4) + fi) * 2048 + lane * 8;
#pragma unroll
        for (int ks = 0; ks < 4; ++ks)
            af[fi][ks] = *(const half8*)(ap + ks * 512) * (half_t)(-2.0f);
    }

    // owned C-rows: rowbase + fi*16 + lrow*4 + rg
    const int ibase = rowbase + lrow * 4;
    int li[16];
#pragma unroll
    for (int fi = 0; fi < 4; ++fi)
#pragma unroll
        for (int rg = 0; rg < 4; ++rg)
            li[fi * 4 + rg] = labels[ibase + fi * 16 + rg];

    float mpos[16], mneg[16];
#pragma unroll
    for (int r = 0; r < 16; ++r) { mpos[r] = -1e38f; mneg[r] = 1e38f; }

    asm volatile("s_waitcnt vmcnt(0)" ::: "memory");
    __builtin_amdgcn_s_barrier();
    __builtin_amdgcn_sched_barrier(0);

    // ---- 16 substeps of 16 cols; 2-phase: stage t+1, compute t, drain ----
#pragma unroll
    for (int t = 0; t < 16; ++t) {
        if (t < 15 && tid < 256)
            __builtin_amdgcn_global_load_lds(
                AS1C(xp + ((size_t)(colbase >> 4) + t + 1) * 2048 + tid * 8),
                AS3(&Bs[(t + 1) & 1][tid * 8]), 16, 0, 0);

        const half_t* bp = &Bs[t & 1][lane * 8];
        half8 bv0 = *(const half8*)bp;
        half8 bv1 = *(const half8*)(bp + 512);
        half8 bv2 = *(const half8*)(bp + 1024);
        half8 bv3 = *(const half8*)(bp + 1536);
        float2 p = Lns[t * 16 + lcol];
        const int   lj = __float_as_int(p.x);
        const float nj = p.y;

        f32x4 njq = {nj, nj, nj, nj};
        __builtin_amdgcn_s_setprio(1);
        f32x4 a0 = __builtin_amdgcn_mfma_f32_16x16x32_f16(af[0][0], bv0, njq, 0, 0, 0);
        f32x4 a1 = __builtin_amdgcn_mfma_f32_16x16x32_f16(af[1][0], bv0, njq, 0, 0, 0);
        f32x4 a2 = __builtin_amdgcn_mfma_f32_16x16x32_f16(af[2][0], bv0, njq, 0, 0, 0);
        f32x4 a3 = __builtin_amdgcn_mfma_f32_16x16x32_f16(af[3][0], bv0, njq, 0, 0, 0);
        a0 = __builtin_amdgcn_mfma_f32_16x16x32_f16(af[0][1], bv1, a0, 0, 0, 0);
        a1 = __builtin_amdgcn_mfma_f32_16x16x32_f16(af[1][1], bv1, a1, 0, 0, 0);
        a2 = __builtin_amdgcn_mfma_f32_16x16x32_f16(af[2][1], bv1, a2, 0, 0, 0);
        a3 = __builtin_amdgcn_mfma_f32_16x16x32_f16(af[3][1], bv1, a3, 0, 0, 0);
        a0 = __builtin_amdgcn_mfma_f32_16x16x32_f16(af[0][2], bv2, a0, 0, 0, 0);
        a1 = __builtin_amdgcn_mfma_f32_16x16x32_f16(af[1][2], bv2, a1, 0, 0, 0);
        a2 = __builtin_amdgcn_mfma_f32_16x16x32_f16(af[2][2], bv2, a2, 0, 0, 0);
        a3 = __builtin_amdgcn_mfma_f32_16x16x32_f16(af[3][2], bv2, a3, 0, 0, 0);
        a0 = __builtin_amdgcn_mfma_f32_16x16x32_f16(af[0][3], bv3, a0, 0, 0, 0);
        a1 = __builtin_amdgcn_mfma_f32_16x16x32_f16(af[1][3], bv3, a1, 0, 0, 0);
        a2 = __builtin_amdgcn_mfma_f32_16x16x32_f16(af[2][3], bv3, a2, 0, 0, 0);
        a3 = __builtin_amdgcn_mfma_f32_16x16x32_f16(af[3][3], bv3, a3, 0, 0, 0);
        __builtin_amdgcn_s_setprio(0);

        const int dj = colbase + t * 16 - rowbase;
        if (dj == 0)       POISON(a0)
        else if (dj == 16) POISON(a1)
        else if (dj == 32) POISON(a2)
        else if (dj == 48) POISON(a3)
        EPI(a0, 0, lj)
        EPI(a1, 1, lj)
        EPI(a2, 2, lj)
        EPI(a3, 3, lj)

        asm volatile("s_waitcnt vmcnt(0)" ::: "memory");
        __builtin_amdgcn_s_barrier();
        __builtin_amdgcn_sched_barrier(0);
    }

    // reduce across the 16 col-lanes (C cols live on lcol)
#pragma unroll
    for (int o = 1; o < 16; o <<= 1) {
#pragma unroll
        for (int r = 0; r < 16; ++r) {
            mpos[r] = fmaxf(mpos[r], __shfl_xor(mpos[r], o));
            mneg[r] = fminf(mneg[r], __shfl_xor(mneg[r], o));
        }
    }
    if (lcol == 0) {
#pragma unroll
        for (int fi = 0; fi < 4; ++fi)
#pragma unroll
            for (int rg = 0; rg < 4; ++rg) {
                int row = ibase + fi * 16 + rg;
                ppos[(size_t)row * 32 + chunk] = mpos[fi * 4 + rg];
                pneg[(size_t)row * 32 + chunk] = mneg[fi * 4 + rg];
            }
    }
}

// ---------------- finalize rows + global mean (last-block ticket) ------------
__global__ void triplet_reduce(const float* __restrict__ ppos,
                               const float* __restrict__ pneg,
                               const float2* __restrict__ lnjg,
                               float* __restrict__ gacc,
                               float* __restrict__ out) {
    __shared__ float ss[256];
    __shared__ float sc[256];
    const int tid = threadIdx.x;
    const int r   = blockIdx.x * 256 + tid;
    float mp = -1e38f, mn = 1e38f;
    const f32x4* pp = (const f32x4*)(ppos + (size_t)r * 32);
    const f32x4* pn = (const f32x4*)(pneg + (size_t)r * 32);
#pragma unroll
    for (int s4 = 0; s4 < 8; ++s4) {
        f32x4 a = pp[s4], b = pn[s4];
#pragma unroll
        for (int e = 0; e < 4; ++e) { mp = fmaxf(mp, a[e]); mn = fminf(mn, b[e]); }
    }
    float ni = lnjg[r].y;
    bool valid = (mp > -1e37f) && (mn < 1e37f);
    float hp = sqrtf(fmaxf(ni + mp, 0.f));
    float hn = sqrtf(fmaxf(ni + mn, 0.f));
    float pr = fmaxf(hp - hn + MARGIN, 0.f);
    ss[tid] = valid ? pr : 0.f;
    sc[tid] = valid ? 1.f : 0.f;
    __syncthreads();
    for (int o = 128; o > 0; o >>= 1) {
        if (tid < o) { ss[tid] += ss[tid + o]; sc[tid] += sc[tid + o]; }
        __syncthreads();
    }
    if (tid == 0) {
        atomicAdd(&gacc[0], ss[0]);
        atomicAdd(&gacc[1], sc[0]);
        __threadfence();
        unsigned* ticket = (unsigned*)(gacc + 2);
        unsigned old = atomicAdd(ticket, 1u);
        if (old == gridDim.x - 1) {
            float s = atomicAdd(&gacc[0], 0.f);
            float c = atomicAdd(&gacc[1], 0.f);
            out[0] = (c > 0.f) ? (s / c) : 0.f;
        }
    }
}

// -----------------------------------------------------------------------------
extern "C" void kernel_launch(void* const* d_in, const int* in_sizes, int n_in,
                              void* d_out, int out_size, void* d_ws, size_t ws_size,
                              hipStream_t stream) {
    const float* x      = (const float*)d_in[0];
    const int*   labels = (const int*)d_in[1];
    float*       out    = (float*)d_out;

    // ws layout: xp (2 MiB) | lnj (64 KiB) | ppos (1 MiB) | pneg (1 MiB) | gacc (12 B)
    char*   ws    = (char*)d_ws;
    half_t* xp    = (half_t*)ws;
    float2* lnj   = (float2*)(ws + (size_t)N * D * sizeof(half_t));
    float*  ppos  = (float*)(lnj + N);
    float*  pneg  = ppos + (size_t)N * 32;
    float*  gacc  = pneg + (size_t)N * 32;

    triplet_prep  <<<N / 16,   256, 0, stream>>>(x, labels, xp, lnj, gacc);
    triplet_main  <<<512,      512, 0, stream>>>(xp, lnj, labels, ppos, pneg);
    triplet_reduce<<<N / 256,  256, 0, stream>>>(ppos, pneg, lnj, gacc, out);
}